// Round 3
// baseline (359.931 us; speedup 1.0000x reference)
//
#include <hip/hip_runtime.h>
#include <stdint.h>

typedef unsigned short u16;
typedef __bf16 bf16x8 __attribute__((ext_vector_type(8)));
typedef float f32x4 __attribute__((ext_vector_type(4)));

#define MFMA16(a, b, c) __builtin_amdgcn_mfma_f32_16x16x32_bf16(a, b, c, 0, 0, 0)

__device__ __forceinline__ float b2f(u16 u) { return __uint_as_float(((uint32_t)u) << 16); }
__device__ __forceinline__ u16 f2b(float f) {
    uint32_t x = __float_as_uint(f);
    return (u16)((x + 0x7fffu + ((x >> 16) & 1u)) >> 16);
}

// dtype discriminator: sin_enc[0]=sin(0)=0.0, sin_enc[1]=cos(0)=1.0 in EITHER dtype.
// First 32-bit word: bf16 -> 0x3F800000 ([0x0000,0x3F80]); f32 -> 0x00000000.
__device__ __forceinline__ int input_is_bf16(const void* sin_enc) {
    return (*(const uint32_t*)sin_enc) == 0x3F800000u ? 1 : 0;
}

// scalar load -> f32
template<int BF16>
__device__ __forceinline__ float ldf(const void* p, size_t i) {
    if (BF16) return b2f(((const u16*)p)[i]);
    return ((const float*)p)[i];
}
// 8 consecutive elements -> bf16x8 (for MFMA staging)
template<int BF16>
__device__ __forceinline__ bf16x8 ld8(const void* p, size_t i) {
    if (BF16) {
        uint4 r = *(const uint4*)((const u16*)p + i);
        return *(bf16x8*)&r;
    } else {
        const float* f = (const float*)p + i;
        float4 a = *(const float4*)f;
        float4 b = *(const float4*)(f + 4);
        bf16x8 o;
        o[0] = (__bf16)a.x; o[1] = (__bf16)a.y; o[2] = (__bf16)a.z; o[3] = (__bf16)a.w;
        o[4] = (__bf16)b.x; o[5] = (__bf16)b.y; o[6] = (__bf16)b.z; o[7] = (__bf16)b.w;
        return o;
    }
}

// ---------------------------------------------------------------------------
// Kernel 1: fused QKV projection + bias + RoPE + head split.
// Grid: (24, 32). blockIdx.x: [0,8)->Q, [8,16)->K, [16,24)->V ; 128x128 tile.
// qh,kh: (B,H,L,64) bf16 ; vt: (B,H,64,L) bf16 (transposed, PV MFMA B-operand)
// ---------------------------------------------------------------------------
template<int BF16>
__global__ __launch_bounds__(256) void gemm_proj(
    const void* __restrict__ qin, const void* __restrict__ kin, const void* __restrict__ vin,
    const void* __restrict__ Wq, const void* __restrict__ bq,
    const void* __restrict__ Wk, const void* __restrict__ bk,
    const void* __restrict__ Wv, const void* __restrict__ bv,
    const void* __restrict__ sin_enc,
    u16* __restrict__ qh, u16* __restrict__ kh, u16* __restrict__ vt)
{
    if (input_is_bf16(sin_enc) != BF16) return;
    __shared__ __align__(16) u16 lA[128 * 32];
    __shared__ __align__(16) u16 lB[128 * 32];
    const int t = threadIdx.x, wave = t >> 6, lane = t & 63;
    const int bx = blockIdx.x;
    const int w_idx = bx >> 3;
    const int n0 = (bx & 7) << 7;
    const int m0 = blockIdx.y << 7;
    const void* A    = (w_idx == 0) ? qin : (w_idx == 1 ? kin : vin);
    const void* W    = (w_idx == 0) ? Wq  : (w_idx == 1 ? Wk  : Wv);
    const void* bias = (w_idx == 0) ? bq  : (w_idx == 1 ? bk  : bv);

    const int wr = wave >> 1, wc = wave & 1;
    const int col16 = lane & 15, g16 = lane >> 4;
    f32x4 acc[4][4] = {};

    // chunk c covers lA elements [8c,8c+8): row c>>2 (of 128), k (c&3)*8 (of 32)
    const int c0   = wave * 128 + lane;
    const int row0 = c0 >> 2;
    const int kp   = (c0 & 3) << 3;
    const size_t gA0 = (size_t)(m0 + row0) * 1024 + kp;
    const size_t gB0 = (size_t)(n0 + row0) * 1024 + kp;
    u16* wA0 = lA + c0 * 8;
    u16* wA1 = lA + (c0 + 64) * 8;   // row0+16
    u16* wB0 = lB + c0 * 8;
    u16* wB1 = lB + (c0 + 64) * 8;

    bf16x8 ra0 = ld8<BF16>(A, gA0);
    bf16x8 ra1 = ld8<BF16>(A, gA0 + 16 * 1024);
    bf16x8 rb0 = ld8<BF16>(W, gB0);
    bf16x8 rb1 = ld8<BF16>(W, gB0 + 16 * 1024);

    for (int kk = 32; kk <= 1024; kk += 32) {
        __syncthreads();                       // prior iter's LDS reads done
        *(bf16x8*)wA0 = ra0; *(bf16x8*)wA1 = ra1;
        *(bf16x8*)wB0 = rb0; *(bf16x8*)wB1 = rb1;
        __syncthreads();                       // writes visible
        if (kk < 1024) {                       // prefetch next tile (overlaps MFMA)
            ra0 = ld8<BF16>(A, gA0 + kk);
            ra1 = ld8<BF16>(A, gA0 + kk + 16 * 1024);
            rb0 = ld8<BF16>(W, gB0 + kk);
            rb1 = ld8<BF16>(W, gB0 + kk + 16 * 1024);
        }
        const u16* pA = lA + (wr * 64 + col16) * 32 + g16 * 8;
        const u16* pB = lB + (wc * 64 + col16) * 32 + g16 * 8;
        bf16x8 af[4], bfr[4];
#pragma unroll
        for (int i = 0; i < 4; i++) {
            af[i]  = *(const bf16x8*)(pA + i * 512);
            bfr[i] = *(const bf16x8*)(pB + i * 512);
        }
#pragma unroll
        for (int mi = 0; mi < 4; mi++)
#pragma unroll
            for (int ni = 0; ni < 4; ni++)
                acc[mi][ni] = MFMA16(af[mi], bfr[ni], acc[mi][ni]);
    }

    // epilogue: bias + rope(+scale for Q) + head-split store
#pragma unroll
    for (int ni = 0; ni < 4; ni++) {
        const int n = n0 + wc * 64 + ni * 16 + col16;   // 0..1023 feature idx
        const float bn = ldf<BF16>(bias, n);
        const int h = n >> 6, hd = n & 63;
#pragma unroll
        for (int mi = 0; mi < 4; mi++) {
#pragma unroll
            for (int r = 0; r < 4; r++) {
                const int m = m0 + wr * 64 + mi * 16 + g16 * 4 + r;
                const int b = m >> 9, l = m & 511;
                float x = acc[mi][ni][r] + bn;
                if (w_idx == 2) {
                    vt[((size_t)(b * 16 + h) * 64 + hd) * 512 + l] = f2b(x);
                } else {
                    float partner = __shfl_xor(x, 1);   // feature n^1, same row
                    float s = ldf<BF16>(sin_enc, (size_t)l * 1024 + (n & ~1));
                    float c = ldf<BF16>(sin_enc, (size_t)l * 1024 + (n | 1));
                    float y = (n & 1) ? (x * c + partner * s) : (x * c - partner * s);
                    if (w_idx == 0) y *= 0.125f;  // 1/sqrt(64)
                    u16* dst = (w_idx == 0) ? qh : kh;
                    dst[((size_t)(b * 16 + h) * 512 + l) * 64 + hd] = f2b(y);
                }
            }
        }
    }
}

// ---------------------------------------------------------------------------
// Kernel 2: flash attention with dist bias + key mask.
// Grid: 1024 blocks (= B*H * 8 q-tiles), 256 threads.
// ---------------------------------------------------------------------------
template<int BF16>
__global__ __launch_bounds__(256) void attn_kernel(
    const u16* __restrict__ qh, const u16* __restrict__ kh, const u16* __restrict__ vt,
    const void* __restrict__ demb_g, const int* __restrict__ length,
    const int* __restrict__ dist, const void* __restrict__ sin_enc,
    u16* __restrict__ ctx)
{
    if (input_is_bf16(sin_enc) != BF16) return;
    __shared__ __align__(16) u16 Qs[64 * 64];
    __shared__ __align__(16) u16 Ks[64 * 64];
    __shared__ __align__(16) u16 Vs[64 * 64];    // [d][k]
    __shared__ __align__(16) u16 Ps[4][16 * 64]; // per-wave P tile
    __shared__ float demb[64];

    const int t = threadIdx.x, wave = t >> 6, lane = t & 63;
    const int bxx = blockIdx.x;
    const int qt = bxx & 7, bh = bxx >> 3;
    const int b = bh >> 4, h = bh & 15;
    if (t < 64) demb[t] = ldf<BF16>(demb_g, t * 16 + h);
    const int len_b = length[b];
    const int col16 = lane & 15, g16 = lane >> 4;
    const int c0 = wave * 128 + lane, c1 = c0 + 64;

    // stage Q tile (64 rows x 64 dims, contiguous 8KB) via registers
    const u16* qbase = qh + (size_t)(bh * 512 + qt * 64) * 64;
    {
        uint4 rq0 = *(const uint4*)(qbase + c0 * 8);
        uint4 rq1 = *(const uint4*)(qbase + c1 * 8);
        *(uint4*)((char*)Qs + c0 * 16) = rq0;
        *(uint4*)((char*)Qs + c1 * 16) = rq1;
    }

    const u16* kbase = kh + (size_t)bh * 512 * 64;
    const u16* vbase = vt + (size_t)bh * 64 * 512;
    const int* dist_b = dist + (size_t)b * 512 * 512;
    const int qrow_base = qt * 64 + wave * 16 + g16 * 4;

    // preload kt=0 K/V chunks
    uint4 rk0 = *(const uint4*)(kbase + c0 * 8);
    uint4 rk1 = *(const uint4*)(kbase + c1 * 8);
    uint4 rv0 = *(const uint4*)(vbase + (size_t)(c0 >> 3) * 512 + (c0 & 7) * 8);
    uint4 rv1 = *(const uint4*)(vbase + (size_t)(c1 >> 3) * 512 + (c1 & 7) * 8);

    __syncthreads();   // Qs + demb visible
    const u16* pQ = Qs + (wave * 16 + col16) * 64 + g16 * 8;
    const bf16x8 qa0 = *(const bf16x8*)pQ;
    const bf16x8 qa1 = *(const bf16x8*)(pQ + 32);

    f32x4 oacc[4] = {};
    float mrow[4], lrow[4];
#pragma unroll
    for (int r = 0; r < 4; r++) { mrow[r] = -1e30f; lrow[r] = 0.f; }

    for (int kt = 0; kt < 8; kt++) {
        __syncthreads();   // prior iteration's Ks/Vs/Ps reads done
        *(uint4*)((char*)Ks + c0 * 16) = rk0;
        *(uint4*)((char*)Ks + c1 * 16) = rk1;
        *(uint4*)((char*)Vs + c0 * 16) = rv0;
        *(uint4*)((char*)Vs + c1 * 16) = rv1;
        __syncthreads();
        if (kt < 7) {      // prefetch next K/V tile (overlaps compute)
            const u16* kb = kbase + (size_t)(kt + 1) * 64 * 64;
            rk0 = *(const uint4*)(kb + c0 * 8);
            rk1 = *(const uint4*)(kb + c1 * 8);
            rv0 = *(const uint4*)(vbase + (size_t)(c0 >> 3) * 512 + (kt + 1) * 64 + (c0 & 7) * 8);
            rv1 = *(const uint4*)(vbase + (size_t)(c1 >> 3) * 512 + (kt + 1) * 64 + (c1 & 7) * 8);
        }

        // S = Q K^T  (16 q rows x 64 keys per wave)
        f32x4 sacc[4] = {};
#pragma unroll
        for (int ni = 0; ni < 4; ni++) {
            const u16* pK = Ks + (ni * 16 + col16) * 64 + g16 * 8;
            bf16x8 kf0 = *(const bf16x8*)pK;
            bf16x8 kf1 = *(const bf16x8*)(pK + 32);
            sacc[ni] = MFMA16(qa0, kf0, sacc[ni]);
            sacc[ni] = MFMA16(qa1, kf1, sacc[ni]);
        }

        // dist bias + key mask
        float rmax[4] = {-1e30f, -1e30f, -1e30f, -1e30f};
#pragma unroll
        for (int ni = 0; ni < 4; ni++) {
            const int kcol = kt * 64 + ni * 16 + col16;
            const bool masked = kcol >= len_b;
#pragma unroll
            for (int r = 0; r < 4; r++) {
                const int qrow = qrow_base + r;
                float s = sacc[ni][r] + demb[dist_b[(size_t)qrow * 512 + kcol] & 63];
                s = masked ? -1e9f : s;
                sacc[ni][r] = s;
                rmax[r] = fmaxf(rmax[r], s);
            }
        }
#pragma unroll
        for (int off = 1; off < 16; off <<= 1)
#pragma unroll
            for (int r = 0; r < 4; r++) rmax[r] = fmaxf(rmax[r], __shfl_xor(rmax[r], off));

        float alpha[4], rsum[4];
#pragma unroll
        for (int r = 0; r < 4; r++) {
            float mn = fmaxf(mrow[r], rmax[r]);
            alpha[r] = __expf(mrow[r] - mn);   // first tile: underflows to 0
            mrow[r] = mn;
            rsum[r] = 0.f;
        }
#pragma unroll
        for (int ni = 0; ni < 4; ni++)
#pragma unroll
            for (int r = 0; r < 4; r++) {
                float p = __expf(sacc[ni][r] - mrow[r]);
                sacc[ni][r] = p;
                rsum[r] += p;
            }
#pragma unroll
        for (int off = 1; off < 16; off <<= 1)
#pragma unroll
            for (int r = 0; r < 4; r++) rsum[r] += __shfl_xor(rsum[r], off);
#pragma unroll
        for (int r = 0; r < 4; r++) lrow[r] = lrow[r] * alpha[r] + rsum[r];
#pragma unroll
        for (int di = 0; di < 4; di++)
#pragma unroll
            for (int r = 0; r < 4; r++) oacc[di][r] *= alpha[r];

        // P: C/D layout -> LDS -> A-frag layout (wave-private region)
        u16* Pw = &Ps[wave][0];
#pragma unroll
        for (int ni = 0; ni < 4; ni++)
#pragma unroll
            for (int r = 0; r < 4; r++)
                Pw[(g16 * 4 + r) * 64 + ni * 16 + col16] = f2b(sacc[ni][r]);
        __syncthreads();

        const u16* pP = Pw + col16 * 64 + g16 * 8;
        bf16x8 pa0 = *(const bf16x8*)pP;
        bf16x8 pa1 = *(const bf16x8*)(pP + 32);
#pragma unroll
        for (int di = 0; di < 4; di++) {
            const u16* pV = Vs + (di * 16 + col16) * 64 + g16 * 8;
            bf16x8 vf0 = *(const bf16x8*)pV;
            bf16x8 vf1 = *(const bf16x8*)(pV + 32);
            oacc[di] = MFMA16(pa0, vf0, oacc[di]);
            oacc[di] = MFMA16(pa1, vf1, oacc[di]);
        }
    }

    // epilogue: O/l -> ctx (B,L,D) merged heads (bf16 workspace)
#pragma unroll
    for (int di = 0; di < 4; di++)
#pragma unroll
        for (int r = 0; r < 4; r++) {
            const int qrow = qrow_base + r;
            const int d = di * 16 + col16;
            const float inv_l = 1.0f / fmaxf(lrow[r], 1e-30f);
            ctx[(size_t)(b * 512 + qrow) * 1024 + h * 64 + d] = f2b(oacc[di][r] * inv_l);
        }
}

// ---------------------------------------------------------------------------
// Kernel 3: output projection ctx @ Wo^T + bo -> out (input dtype). Grid: (8,32).
// ---------------------------------------------------------------------------
template<int BF16>
__global__ __launch_bounds__(256) void gemm_out(
    const u16* __restrict__ ctx, const void* __restrict__ Wo,
    const void* __restrict__ bo, const void* __restrict__ sin_enc,
    void* __restrict__ out)
{
    if (input_is_bf16(sin_enc) != BF16) return;
    __shared__ __align__(16) u16 lA[128 * 32];
    __shared__ __align__(16) u16 lB[128 * 32];
    const int t = threadIdx.x, wave = t >> 6, lane = t & 63;
    const int n0 = blockIdx.x << 7;
    const int m0 = blockIdx.y << 7;
    const int wr = wave >> 1, wc = wave & 1;
    const int col16 = lane & 15, g16 = lane >> 4;
    f32x4 acc[4][4] = {};

    const int c0   = wave * 128 + lane;
    const int row0 = c0 >> 2;
    const int kp   = (c0 & 3) << 3;
    const u16* gA = ctx + (size_t)(m0 + row0) * 1024 + kp;
    const size_t gB0 = (size_t)(n0 + row0) * 1024 + kp;
    u16* wA0 = lA + c0 * 8;
    u16* wA1 = lA + (c0 + 64) * 8;
    u16* wB0 = lB + c0 * 8;
    u16* wB1 = lB + (c0 + 64) * 8;

    uint4 ua0 = *(const uint4*)gA;
    uint4 ua1 = *(const uint4*)(gA + 16 * 1024);
    bf16x8 ra0 = *(bf16x8*)&ua0, ra1 = *(bf16x8*)&ua1;
    bf16x8 rb0 = ld8<BF16>(Wo, gB0);
    bf16x8 rb1 = ld8<BF16>(Wo, gB0 + 16 * 1024);

    for (int kk = 32; kk <= 1024; kk += 32) {
        __syncthreads();
        *(bf16x8*)wA0 = ra0; *(bf16x8*)wA1 = ra1;
        *(bf16x8*)wB0 = rb0; *(bf16x8*)wB1 = rb1;
        __syncthreads();
        if (kk < 1024) {
            uint4 t0 = *(const uint4*)(gA + kk);
            uint4 t1 = *(const uint4*)(gA + kk + 16 * 1024);
            ra0 = *(bf16x8*)&t0; ra1 = *(bf16x8*)&t1;
            rb0 = ld8<BF16>(Wo, gB0 + kk);
            rb1 = ld8<BF16>(Wo, gB0 + kk + 16 * 1024);
        }
        const u16* pA = lA + (wr * 64 + col16) * 32 + g16 * 8;
        const u16* pB = lB + (wc * 64 + col16) * 32 + g16 * 8;
        bf16x8 af[4], bfr[4];
#pragma unroll
        for (int i = 0; i < 4; i++) {
            af[i]  = *(const bf16x8*)(pA + i * 512);
            bfr[i] = *(const bf16x8*)(pB + i * 512);
        }
#pragma unroll
        for (int mi = 0; mi < 4; mi++)
#pragma unroll
            for (int ni = 0; ni < 4; ni++)
                acc[mi][ni] = MFMA16(af[mi], bfr[ni], acc[mi][ni]);
    }

#pragma unroll
    for (int ni = 0; ni < 4; ni++) {
        const int n = n0 + wc * 64 + ni * 16 + col16;
        const float bn = ldf<BF16>(bo, n);
#pragma unroll
        for (int mi = 0; mi < 4; mi++)
#pragma unroll
            for (int r = 0; r < 4; r++) {
                const int m = m0 + wr * 64 + mi * 16 + g16 * 4 + r;
                const float val = acc[mi][ni][r] + bn;
                if (BF16) ((u16*)out)[(size_t)m * 1024 + n] = f2b(val);
                else      ((float*)out)[(size_t)m * 1024 + n] = val;
            }
    }
}

extern "C" void kernel_launch(void* const* d_in, const int* in_sizes, int n_in,
                              void* d_out, int out_size, void* d_ws, size_t ws_size,
                              hipStream_t stream) {
    const void* q       = d_in[0];
    const void* k       = d_in[1];
    const void* v       = d_in[2];
    const void* Wq      = d_in[3];
    const void* bq      = d_in[4];
    const void* Wk      = d_in[5];
    const void* bk      = d_in[6];
    const void* Wv      = d_in[7];
    const void* bv      = d_in[8];
    const void* Wo      = d_in[9];
    const void* bo      = d_in[10];
    const void* demb    = d_in[11];
    const void* sin_enc = d_in[12];
    const int* length   = (const int*)d_in[13];
    const int* dist     = (const int*)d_in[14];

    const size_t QTR = 4194304;            // 8 MB region, in u16 elements
    u16* qh  = (u16*)d_ws;                 // (B,H,L,64)
    u16* kh  = qh + QTR;                   // (B,H,L,64)
    u16* vt  = kh + QTR;                   // (B,H,64,L)
    u16* ctx = vt + QTR;                   // (B,L,D)

    // Both dtype variants are launched every call; each early-exits unless the
    // device-side discriminator (sin_enc word 0) matches. Same work every call.
    gemm_proj<1><<<dim3(24, 32), 256, 0, stream>>>(q, k, v, Wq, bq, Wk, bk, Wv, bv,
                                                   sin_enc, qh, kh, vt);
    gemm_proj<0><<<dim3(24, 32), 256, 0, stream>>>(q, k, v, Wq, bq, Wk, bk, Wv, bv,
                                                   sin_enc, qh, kh, vt);
    attn_kernel<1><<<dim3(1024), 256, 0, stream>>>(qh, kh, vt, demb, length, dist,
                                                   sin_enc, ctx);
    attn_kernel<0><<<dim3(1024), 256, 0, stream>>>(qh, kh, vt, demb, length, dist,
                                                   sin_enc, ctx);
    gemm_out<1><<<dim3(8, 32), 256, 0, stream>>>(ctx, Wo, bo, sin_enc, d_out);
    gemm_out<0><<<dim3(8, 32), 256, 0, stream>>>(ctx, Wo, bo, sin_enc, d_out);
}

// Round 4
// 287.418 us; speedup vs baseline: 1.2523x; 1.2523x over previous
//
#include <hip/hip_runtime.h>
#include <stdint.h>

typedef unsigned short u16;
typedef __bf16 bf16x8 __attribute__((ext_vector_type(8)));
typedef float f32x4 __attribute__((ext_vector_type(4)));

#define MFMA16(a, b, c) __builtin_amdgcn_mfma_f32_16x16x32_bf16(a, b, c, 0, 0, 0)

__device__ __forceinline__ float b2f(u16 u) { return __uint_as_float(((uint32_t)u) << 16); }
__device__ __forceinline__ u16 f2b(float f) {
    uint32_t x = __float_as_uint(f);
    return (u16)((x + 0x7fffu + ((x >> 16) & 1u)) >> 16);
}
// async global->LDS, 16B per lane; lds dest = wave-uniform base + lane*16
__device__ __forceinline__ void load16(const void* g, void* l) {
    __builtin_amdgcn_global_load_lds(
        (const __attribute__((address_space(1))) uint32_t*)(uintptr_t)g,
        (__attribute__((address_space(3))) uint32_t*)(uint32_t)(uintptr_t)l,
        16, 0, 0);
}
// 8 consecutive f32 -> bf16x8
__device__ __forceinline__ bf16x8 ld8f(const float* f) {
    float4 a = *(const float4*)f;
    float4 b = *(const float4*)(f + 4);
    bf16x8 o;
    o[0] = (__bf16)a.x; o[1] = (__bf16)a.y; o[2] = (__bf16)a.z; o[3] = (__bf16)a.w;
    o[4] = (__bf16)b.x; o[5] = (__bf16)b.y; o[6] = (__bf16)b.z; o[7] = (__bf16)b.w;
    return o;
}

// ---------------------------------------------------------------------------
// Kernel 0 (fast path): f32 -> bf16 conversion of q,k,v,Wq,Wk,Wv,Wo.
// grid (2048, 7); y selects tensor; 8 elems/thread.
// ---------------------------------------------------------------------------
__global__ __launch_bounds__(256) void convert_k(
    const float* __restrict__ q, const float* __restrict__ k, const float* __restrict__ v,
    const float* __restrict__ Wq, const float* __restrict__ Wk,
    const float* __restrict__ Wv, const float* __restrict__ Wo,
    u16* __restrict__ qb, u16* __restrict__ kb, u16* __restrict__ vb,
    u16* __restrict__ wqb, u16* __restrict__ wkb, u16* __restrict__ wvb,
    u16* __restrict__ wob)
{
    const float* src; u16* dst; int n8;
    switch (blockIdx.y) {
        case 0: src = q;  dst = qb;  n8 = 524288; break;
        case 1: src = k;  dst = kb;  n8 = 524288; break;
        case 2: src = v;  dst = vb;  n8 = 524288; break;
        case 3: src = Wq; dst = wqb; n8 = 131072; break;
        case 4: src = Wk; dst = wkb; n8 = 131072; break;
        case 5: src = Wv; dst = wvb; n8 = 131072; break;
        default: src = Wo; dst = wob; n8 = 131072; break;
    }
    int i = blockIdx.x * 256 + threadIdx.x;
    if (i >= n8) return;
    bf16x8 o = ld8f(src + (size_t)i * 8);
    *(bf16x8*)(dst + (size_t)i * 8) = o;
}

// ---------------------------------------------------------------------------
// Kernel 1 (fast path): bf16 QKV projection + bias + RoPE + head split.
// Grid (24, 32); bx>>3 selects Q/K/V; 128x128 tile, BK=32, global_load_lds.
// qh,kh: (B,H,L,64) bf16 ; vt: (B,H,64,L) bf16
// ---------------------------------------------------------------------------
__global__ __launch_bounds__(256) void gemm_proj_b(
    const u16* __restrict__ qb, const u16* __restrict__ kb, const u16* __restrict__ vb,
    const u16* __restrict__ wqb, const u16* __restrict__ wkb, const u16* __restrict__ wvb,
    const float* __restrict__ bq, const float* __restrict__ bk, const float* __restrict__ bv,
    const float* __restrict__ sin_enc,
    u16* __restrict__ qh, u16* __restrict__ kh, u16* __restrict__ vt)
{
    __shared__ __align__(16) u16 lA[128 * 32];
    __shared__ __align__(16) u16 lB[128 * 32];
    const int t = threadIdx.x, wave = t >> 6, lane = t & 63;
    const int bx = blockIdx.x;
    const int w_idx = bx >> 3;
    const int n0 = (bx & 7) << 7;
    const int m0 = blockIdx.y << 7;
    const u16* A = (w_idx == 0) ? qb : (w_idx == 1 ? kb : vb);
    const u16* W = (w_idx == 0) ? wqb : (w_idx == 1 ? wkb : wvb);
    const float* bias = (w_idx == 0) ? bq : (w_idx == 1 ? bk : bv);

    const int wr = wave >> 1, wc = wave & 1;
    const int col16 = lane & 15, g16 = lane >> 4;
    f32x4 acc[4][4] = {};

    const int r0  = wave * 32 + (lane >> 2);
    const int kc8 = (lane & 3) << 3;
    const u16* gA = A + (size_t)(m0 + r0) * 1024 + kc8;
    const u16* gB = W + (size_t)(n0 + r0) * 1024 + kc8;
    char* lA0 = (char*)lA + wave * 2048;
    char* lB0 = (char*)lB + wave * 2048;

    for (int kk = 0; kk < 1024; kk += 32) {
        load16(gA + kk, lA0);
        load16(gA + kk + 16 * 1024, lA0 + 1024);
        load16(gB + kk, lB0);
        load16(gB + kk + 16 * 1024, lB0 + 1024);
        __syncthreads();
        const u16* pA = lA + (wr * 64 + col16) * 32 + g16 * 8;
        const u16* pB = lB + (wc * 64 + col16) * 32 + g16 * 8;
        bf16x8 af[4], bfr[4];
#pragma unroll
        for (int i = 0; i < 4; i++) {
            af[i]  = *(const bf16x8*)(pA + i * 512);
            bfr[i] = *(const bf16x8*)(pB + i * 512);
        }
#pragma unroll
        for (int mi = 0; mi < 4; mi++)
#pragma unroll
            for (int ni = 0; ni < 4; ni++)
                acc[mi][ni] = MFMA16(af[mi], bfr[ni], acc[mi][ni]);
        __syncthreads();
    }

#pragma unroll
    for (int ni = 0; ni < 4; ni++) {
        const int n = n0 + wc * 64 + ni * 16 + col16;
        const float bn = bias[n];
        const int h = n >> 6, hd = n & 63;
#pragma unroll
        for (int mi = 0; mi < 4; mi++) {
#pragma unroll
            for (int r = 0; r < 4; r++) {
                const int m = m0 + wr * 64 + mi * 16 + g16 * 4 + r;
                const int b = m >> 9, l = m & 511;
                float x = acc[mi][ni][r] + bn;
                if (w_idx == 2) {
                    vt[((size_t)(b * 16 + h) * 64 + hd) * 512 + l] = f2b(x);
                } else {
                    float partner = __shfl_xor(x, 1);
                    float s = sin_enc[(size_t)l * 1024 + (n & ~1)];
                    float c = sin_enc[(size_t)l * 1024 + (n | 1)];
                    float y = (n & 1) ? (x * c + partner * s) : (x * c - partner * s);
                    if (w_idx == 0) y *= 0.125f;
                    u16* dst = (w_idx == 0) ? qh : kh;
                    dst[((size_t)(b * 16 + h) * 512 + l) * 64 + hd] = f2b(y);
                }
            }
        }
    }
}

// ---------------------------------------------------------------------------
// Kernel 1 (fallback): f32 inputs, in-register convert (round-3, verified).
// ---------------------------------------------------------------------------
__global__ __launch_bounds__(256) void gemm_proj_f32(
    const float* __restrict__ qin, const float* __restrict__ kin, const float* __restrict__ vin,
    const float* __restrict__ Wq, const float* __restrict__ bq,
    const float* __restrict__ Wk, const float* __restrict__ bk,
    const float* __restrict__ Wv, const float* __restrict__ bv,
    const float* __restrict__ sin_enc,
    u16* __restrict__ qh, u16* __restrict__ kh, u16* __restrict__ vt)
{
    __shared__ __align__(16) u16 lA[128 * 32];
    __shared__ __align__(16) u16 lB[128 * 32];
    const int t = threadIdx.x, wave = t >> 6, lane = t & 63;
    const int bx = blockIdx.x;
    const int w_idx = bx >> 3;
    const int n0 = (bx & 7) << 7;
    const int m0 = blockIdx.y << 7;
    const float* A    = (w_idx == 0) ? qin : (w_idx == 1 ? kin : vin);
    const float* W    = (w_idx == 0) ? Wq  : (w_idx == 1 ? Wk  : Wv);
    const float* bias = (w_idx == 0) ? bq  : (w_idx == 1 ? bk  : bv);

    const int wr = wave >> 1, wc = wave & 1;
    const int col16 = lane & 15, g16 = lane >> 4;
    f32x4 acc[4][4] = {};

    const int c0   = wave * 128 + lane;
    const int row0 = c0 >> 2;
    const int kp   = (c0 & 3) << 3;
    const size_t gA0 = (size_t)(m0 + row0) * 1024 + kp;
    const size_t gB0 = (size_t)(n0 + row0) * 1024 + kp;
    u16* wA0 = lA + c0 * 8;
    u16* wA1 = lA + (c0 + 64) * 8;
    u16* wB0 = lB + c0 * 8;
    u16* wB1 = lB + (c0 + 64) * 8;

    bf16x8 ra0 = ld8f(A + gA0);
    bf16x8 ra1 = ld8f(A + gA0 + 16 * 1024);
    bf16x8 rb0 = ld8f(W + gB0);
    bf16x8 rb1 = ld8f(W + gB0 + 16 * 1024);

    for (int kk = 32; kk <= 1024; kk += 32) {
        __syncthreads();
        *(bf16x8*)wA0 = ra0; *(bf16x8*)wA1 = ra1;
        *(bf16x8*)wB0 = rb0; *(bf16x8*)wB1 = rb1;
        __syncthreads();
        if (kk < 1024) {
            ra0 = ld8f(A + gA0 + kk);
            ra1 = ld8f(A + gA0 + kk + 16 * 1024);
            rb0 = ld8f(W + gB0 + kk);
            rb1 = ld8f(W + gB0 + kk + 16 * 1024);
        }
        const u16* pA = lA + (wr * 64 + col16) * 32 + g16 * 8;
        const u16* pB = lB + (wc * 64 + col16) * 32 + g16 * 8;
        bf16x8 af[4], bfr[4];
#pragma unroll
        for (int i = 0; i < 4; i++) {
            af[i]  = *(const bf16x8*)(pA + i * 512);
            bfr[i] = *(const bf16x8*)(pB + i * 512);
        }
#pragma unroll
        for (int mi = 0; mi < 4; mi++)
#pragma unroll
            for (int ni = 0; ni < 4; ni++)
                acc[mi][ni] = MFMA16(af[mi], bfr[ni], acc[mi][ni]);
    }

#pragma unroll
    for (int ni = 0; ni < 4; ni++) {
        const int n = n0 + wc * 64 + ni * 16 + col16;
        const float bn = bias[n];
        const int h = n >> 6, hd = n & 63;
#pragma unroll
        for (int mi = 0; mi < 4; mi++) {
#pragma unroll
            for (int r = 0; r < 4; r++) {
                const int m = m0 + wr * 64 + mi * 16 + g16 * 4 + r;
                const int b = m >> 9, l = m & 511;
                float x = acc[mi][ni][r] + bn;
                if (w_idx == 2) {
                    vt[((size_t)(b * 16 + h) * 64 + hd) * 512 + l] = f2b(x);
                } else {
                    float partner = __shfl_xor(x, 1);
                    float s = sin_enc[(size_t)l * 1024 + (n & ~1)];
                    float c = sin_enc[(size_t)l * 1024 + (n | 1)];
                    float y = (n & 1) ? (x * c + partner * s) : (x * c - partner * s);
                    if (w_idx == 0) y *= 0.125f;
                    u16* dst = (w_idx == 0) ? qh : kh;
                    dst[((size_t)(b * 16 + h) * 512 + l) * 64 + hd] = f2b(y);
                }
            }
        }
    }
}

// ---------------------------------------------------------------------------
// Kernel 2 (both paths): flash attention with dist bias + key mask.
// Grid 1024, 256 thr. Early exit: tiles beyond ceil(len_b/64) contribute p=0.
// ---------------------------------------------------------------------------
__global__ __launch_bounds__(256) void attn_kernel(
    const u16* __restrict__ qh, const u16* __restrict__ kh, const u16* __restrict__ vt,
    const float* __restrict__ demb_g, const int* __restrict__ length,
    const int* __restrict__ dist, u16* __restrict__ ctx)
{
    __shared__ __align__(16) u16 Qs[64 * 64];
    __shared__ __align__(16) u16 Ks[64 * 64];
    __shared__ __align__(16) u16 Vs[64 * 64];
    __shared__ __align__(16) u16 Ps[4][16 * 64];
    __shared__ float demb[64];

    const int t = threadIdx.x, wave = t >> 6, lane = t & 63;
    const int bxx = blockIdx.x;
    const int qt = bxx & 7, bh = bxx >> 3;
    const int b = bh >> 4, h = bh & 15;
    if (t < 64) demb[t] = demb_g[t * 16 + h];
    const int len_b = length[b];
    const int ktmax = (len_b + 63) >> 6;   // masked tiles give exactly p=0; skip
    const int col16 = lane & 15, g16 = lane >> 4;
    const int c0 = wave * 128 + lane, c1 = c0 + 64;

    const u16* qbase = qh + (size_t)(bh * 512 + qt * 64) * 64;
    {
        uint4 rq0 = *(const uint4*)(qbase + c0 * 8);
        uint4 rq1 = *(const uint4*)(qbase + c1 * 8);
        *(uint4*)((char*)Qs + c0 * 16) = rq0;
        *(uint4*)((char*)Qs + c1 * 16) = rq1;
    }

    const u16* kbase = kh + (size_t)bh * 512 * 64;
    const u16* vbase = vt + (size_t)bh * 64 * 512;
    const int* dist_b = dist + (size_t)b * 512 * 512;
    const int qrow_base = qt * 64 + wave * 16 + g16 * 4;

    uint4 rk0 = *(const uint4*)(kbase + c0 * 8);
    uint4 rk1 = *(const uint4*)(kbase + c1 * 8);
    uint4 rv0 = *(const uint4*)(vbase + (size_t)(c0 >> 3) * 512 + (c0 & 7) * 8);
    uint4 rv1 = *(const uint4*)(vbase + (size_t)(c1 >> 3) * 512 + (c1 & 7) * 8);

    __syncthreads();
    const u16* pQ = Qs + (wave * 16 + col16) * 64 + g16 * 8;
    const bf16x8 qa0 = *(const bf16x8*)pQ;
    const bf16x8 qa1 = *(const bf16x8*)(pQ + 32);

    f32x4 oacc[4] = {};
    float mrow[4], lrow[4];
#pragma unroll
    for (int r = 0; r < 4; r++) { mrow[r] = -1e30f; lrow[r] = 0.f; }

    for (int kt = 0; kt < ktmax; kt++) {
        __syncthreads();
        *(uint4*)((char*)Ks + c0 * 16) = rk0;
        *(uint4*)((char*)Ks + c1 * 16) = rk1;
        *(uint4*)((char*)Vs + c0 * 16) = rv0;
        *(uint4*)((char*)Vs + c1 * 16) = rv1;
        __syncthreads();
        if (kt + 1 < ktmax) {
            const u16* kb = kbase + (size_t)(kt + 1) * 64 * 64;
            rk0 = *(const uint4*)(kb + c0 * 8);
            rk1 = *(const uint4*)(kb + c1 * 8);
            rv0 = *(const uint4*)(vbase + (size_t)(c0 >> 3) * 512 + (kt + 1) * 64 + (c0 & 7) * 8);
            rv1 = *(const uint4*)(vbase + (size_t)(c1 >> 3) * 512 + (kt + 1) * 64 + (c1 & 7) * 8);
        }

        f32x4 sacc[4] = {};
#pragma unroll
        for (int ni = 0; ni < 4; ni++) {
            const u16* pK = Ks + (ni * 16 + col16) * 64 + g16 * 8;
            bf16x8 kf0 = *(const bf16x8*)pK;
            bf16x8 kf1 = *(const bf16x8*)(pK + 32);
            sacc[ni] = MFMA16(qa0, kf0, sacc[ni]);
            sacc[ni] = MFMA16(qa1, kf1, sacc[ni]);
        }

        float rmax[4] = {-1e30f, -1e30f, -1e30f, -1e30f};
#pragma unroll
        for (int ni = 0; ni < 4; ni++) {
            const int kcol = kt * 64 + ni * 16 + col16;
            const bool masked = kcol >= len_b;
#pragma unroll
            for (int r = 0; r < 4; r++) {
                const int qrow = qrow_base + r;
                float s = sacc[ni][r] + demb[dist_b[(size_t)qrow * 512 + kcol] & 63];
                s = masked ? -1e9f : s;
                sacc[ni][r] = s;
                rmax[r] = fmaxf(rmax[r], s);
            }
        }
#pragma unroll
        for (int off = 1; off < 16; off <<= 1)
#pragma unroll
            for (int r = 0; r < 4; r++) rmax[r] = fmaxf(rmax[r], __shfl_xor(rmax[r], off));

        float alpha[4], rsum[4];
#pragma unroll
        for (int r = 0; r < 4; r++) {
            float mn = fmaxf(mrow[r], rmax[r]);
            alpha[r] = __expf(mrow[r] - mn);
            mrow[r] = mn;
            rsum[r] = 0.f;
        }
#pragma unroll
        for (int ni = 0; ni < 4; ni++)
#pragma unroll
            for (int r = 0; r < 4; r++) {
                float p = __expf(sacc[ni][r] - mrow[r]);
                sacc[ni][r] = p;
                rsum[r] += p;
            }
#pragma unroll
        for (int off = 1; off < 16; off <<= 1)
#pragma unroll
            for (int r = 0; r < 4; r++) rsum[r] += __shfl_xor(rsum[r], off);
#pragma unroll
        for (int r = 0; r < 4; r++) lrow[r] = lrow[r] * alpha[r] + rsum[r];
#pragma unroll
        for (int di = 0; di < 4; di++)
#pragma unroll
            for (int r = 0; r < 4; r++) oacc[di][r] *= alpha[r];

        u16* Pw = &Ps[wave][0];
#pragma unroll
        for (int ni = 0; ni < 4; ni++)
#pragma unroll
            for (int r = 0; r < 4; r++)
                Pw[(g16 * 4 + r) * 64 + ni * 16 + col16] = f2b(sacc[ni][r]);
        __syncthreads();

        const u16* pP = Pw + col16 * 64 + g16 * 8;
        bf16x8 pa0 = *(const bf16x8*)pP;
        bf16x8 pa1 = *(const bf16x8*)(pP + 32);
#pragma unroll
        for (int di = 0; di < 4; di++) {
            const u16* pV = Vs + (di * 16 + col16) * 64 + g16 * 8;
            bf16x8 vf0 = *(const bf16x8*)pV;
            bf16x8 vf1 = *(const bf16x8*)(pV + 32);
            oacc[di] = MFMA16(pa0, vf0, oacc[di]);
            oacc[di] = MFMA16(pa1, vf1, oacc[di]);
        }
    }

#pragma unroll
    for (int di = 0; di < 4; di++)
#pragma unroll
        for (int r = 0; r < 4; r++) {
            const int qrow = qrow_base + r;
            const int d = di * 16 + col16;
            const float inv_l = 1.0f / fmaxf(lrow[r], 1e-30f);
            ctx[(size_t)(b * 512 + qrow) * 1024 + h * 64 + d] = f2b(oacc[di][r] * inv_l);
        }
}

// ---------------------------------------------------------------------------
// Kernel 3 (fast path): ctx(bf16) @ Wo^T(bf16) + bo -> f32 out. Grid (8,32).
// ---------------------------------------------------------------------------
__global__ __launch_bounds__(256) void gemm_out_b(
    const u16* __restrict__ ctx, const u16* __restrict__ wob,
    const float* __restrict__ bo, float* __restrict__ out)
{
    __shared__ __align__(16) u16 lA[128 * 32];
    __shared__ __align__(16) u16 lB[128 * 32];
    const int t = threadIdx.x, wave = t >> 6, lane = t & 63;
    const int n0 = blockIdx.x << 7;
    const int m0 = blockIdx.y << 7;
    const int wr = wave >> 1, wc = wave & 1;
    const int col16 = lane & 15, g16 = lane >> 4;
    f32x4 acc[4][4] = {};

    const int r0  = wave * 32 + (lane >> 2);
    const int kc8 = (lane & 3) << 3;
    const u16* gA = ctx + (size_t)(m0 + r0) * 1024 + kc8;
    const u16* gB = wob + (size_t)(n0 + r0) * 1024 + kc8;
    char* lA0 = (char*)lA + wave * 2048;
    char* lB0 = (char*)lB + wave * 2048;

    for (int kk = 0; kk < 1024; kk += 32) {
        load16(gA + kk, lA0);
        load16(gA + kk + 16 * 1024, lA0 + 1024);
        load16(gB + kk, lB0);
        load16(gB + kk + 16 * 1024, lB0 + 1024);
        __syncthreads();
        const u16* pA = lA + (wr * 64 + col16) * 32 + g16 * 8;
        const u16* pB = lB + (wc * 64 + col16) * 32 + g16 * 8;
        bf16x8 af[4], bfr[4];
#pragma unroll
        for (int i = 0; i < 4; i++) {
            af[i]  = *(const bf16x8*)(pA + i * 512);
            bfr[i] = *(const bf16x8*)(pB + i * 512);
        }
#pragma unroll
        for (int mi = 0; mi < 4; mi++)
#pragma unroll
            for (int ni = 0; ni < 4; ni++)
                acc[mi][ni] = MFMA16(af[mi], bfr[ni], acc[mi][ni]);
        __syncthreads();
    }

#pragma unroll
    for (int ni = 0; ni < 4; ni++) {
        const int n = n0 + wc * 64 + ni * 16 + col16;
        const float bn = bo[n];
#pragma unroll
        for (int mi = 0; mi < 4; mi++)
#pragma unroll
            for (int r = 0; r < 4; r++) {
                const int m = m0 + wr * 64 + mi * 16 + g16 * 4 + r;
                out[(size_t)m * 1024 + n] = acc[mi][ni][r] + bn;
            }
    }
}

// ---------------------------------------------------------------------------
// Kernel 3 (fallback): ctx(bf16) @ Wo^T(f32) + bo -> f32 out (round-3 path).
// ---------------------------------------------------------------------------
__global__ __launch_bounds__(256) void gemm_out_f32(
    const u16* __restrict__ ctx, const float* __restrict__ Wo,
    const float* __restrict__ bo, float* __restrict__ out)
{
    __shared__ __align__(16) u16 lA[128 * 32];
    __shared__ __align__(16) u16 lB[128 * 32];
    const int t = threadIdx.x, wave = t >> 6, lane = t & 63;
    const int n0 = blockIdx.x << 7;
    const int m0 = blockIdx.y << 7;
    const int wr = wave >> 1, wc = wave & 1;
    const int col16 = lane & 15, g16 = lane >> 4;
    f32x4 acc[4][4] = {};

    const int c0   = wave * 128 + lane;
    const int row0 = c0 >> 2;
    const int kp   = (c0 & 3) << 3;
    const u16* gA = ctx + (size_t)(m0 + row0) * 1024 + kp;
    const size_t gB0 = (size_t)(n0 + row0) * 1024 + kp;
    u16* wA0 = lA + c0 * 8;
    u16* wA1 = lA + (c0 + 64) * 8;
    u16* wB0 = lB + c0 * 8;
    u16* wB1 = lB + (c0 + 64) * 8;

    uint4 ua0 = *(const uint4*)gA;
    uint4 ua1 = *(const uint4*)(gA + 16 * 1024);
    bf16x8 ra0 = *(bf16x8*)&ua0, ra1 = *(bf16x8*)&ua1;
    bf16x8 rb0 = ld8f(Wo + gB0);
    bf16x8 rb1 = ld8f(Wo + gB0 + 16 * 1024);

    for (int kk = 32; kk <= 1024; kk += 32) {
        __syncthreads();
        *(bf16x8*)wA0 = ra0; *(bf16x8*)wA1 = ra1;
        *(bf16x8*)wB0 = rb0; *(bf16x8*)wB1 = rb1;
        __syncthreads();
        if (kk < 1024) {
            uint4 t0 = *(const uint4*)(gA + kk);
            uint4 t1 = *(const uint4*)(gA + kk + 16 * 1024);
            ra0 = *(bf16x8*)&t0; ra1 = *(bf16x8*)&t1;
            rb0 = ld8f(Wo + gB0 + kk);
            rb1 = ld8f(Wo + gB0 + kk + 16 * 1024);
        }
        const u16* pA = lA + (wr * 64 + col16) * 32 + g16 * 8;
        const u16* pB = lB + (wc * 64 + col16) * 32 + g16 * 8;
        bf16x8 af[4], bfr[4];
#pragma unroll
        for (int i = 0; i < 4; i++) {
            af[i]  = *(const bf16x8*)(pA + i * 512);
            bfr[i] = *(const bf16x8*)(pB + i * 512);
        }
#pragma unroll
        for (int mi = 0; mi < 4; mi++)
#pragma unroll
            for (int ni = 0; ni < 4; ni++)
                acc[mi][ni] = MFMA16(af[mi], bfr[ni], acc[mi][ni]);
    }

#pragma unroll
    for (int ni = 0; ni < 4; ni++) {
        const int n = n0 + wc * 64 + ni * 16 + col16;
        const float bn = bo[n];
#pragma unroll
        for (int mi = 0; mi < 4; mi++)
#pragma unroll
            for (int r = 0; r < 4; r++) {
                const int m = m0 + wr * 64 + mi * 16 + g16 * 4 + r;
                out[(size_t)m * 1024 + n] = acc[mi][ni][r] + bn;
            }
    }
}

extern "C" void kernel_launch(void* const* d_in, const int* in_sizes, int n_in,
                              void* d_out, int out_size, void* d_ws, size_t ws_size,
                              hipStream_t stream) {
    const float* q       = (const float*)d_in[0];
    const float* k       = (const float*)d_in[1];
    const float* v       = (const float*)d_in[2];
    const float* Wq      = (const float*)d_in[3];
    const float* bq      = (const float*)d_in[4];
    const float* Wk      = (const float*)d_in[5];
    const float* bk      = (const float*)d_in[6];
    const float* Wv      = (const float*)d_in[7];
    const float* bv      = (const float*)d_in[8];
    const float* Wo      = (const float*)d_in[9];
    const float* bo      = (const float*)d_in[10];
    const float* demb    = (const float*)d_in[11];
    const float* sin_enc = (const float*)d_in[12];
    const int* length    = (const int*)d_in[13];
    const int* dist      = (const int*)d_in[14];

    const size_t SLOT = 4194304;          // 8 MiB region, in u16 elements
    u16* qh  = (u16*)d_ws;
    u16* kh  = qh + SLOT;
    u16* vt  = kh + SLOT;
    u16* ctx = vt + SLOT;

    if (ws_size >= (size_t)64 * 1024 * 1024) {
        // fast path: one-time f32->bf16 conversion, then pure-bf16 kernels
        u16* qb  = ctx + SLOT;
        u16* kb  = qb + SLOT;
        u16* vb  = kb + SLOT;
        u16* wqb = vb + SLOT;
        u16* wkb = wqb + 1048576;
        u16* wvb = wkb + 1048576;
        u16* wob = wvb + 1048576;
        convert_k<<<dim3(2048, 7), 256, 0, stream>>>(q, k, v, Wq, Wk, Wv, Wo,
                                                     qb, kb, vb, wqb, wkb, wvb, wob);
        gemm_proj_b<<<dim3(24, 32), 256, 0, stream>>>(qb, kb, vb, wqb, wkb, wvb,
                                                      bq, bk, bv, sin_enc, qh, kh, vt);
        attn_kernel<<<dim3(1024), 256, 0, stream>>>(qh, kh, vt, demb, length, dist, ctx);
        gemm_out_b<<<dim3(8, 32), 256, 0, stream>>>(ctx, wob, bo, (float*)d_out);
    } else {
        // fallback (ws >= 32 MiB proven in round 3): f32 staging path
        gemm_proj_f32<<<dim3(24, 32), 256, 0, stream>>>(q, k, v, Wq, bq, Wk, bk, Wv, bv,
                                                        sin_enc, qh, kh, vt);
        attn_kernel<<<dim3(1024), 256, 0, stream>>>(qh, kh, vt, demb, length, dist, ctx);
        gemm_out_f32<<<dim3(8, 32), 256, 0, stream>>>(ctx, Wo, bo, (float*)d_out);
    }
}

// Round 5
// 270.809 us; speedup vs baseline: 1.3291x; 1.0613x over previous
//
#include <hip/hip_runtime.h>
#include <stdint.h>

typedef unsigned short u16;
typedef __bf16 bf16x8 __attribute__((ext_vector_type(8)));
typedef float f32x4 __attribute__((ext_vector_type(4)));

#define MFMA16(a, b, c) __builtin_amdgcn_mfma_f32_16x16x32_bf16(a, b, c, 0, 0, 0)

__device__ __forceinline__ float b2f(u16 u) { return __uint_as_float(((uint32_t)u) << 16); }
__device__ __forceinline__ u16 f2b(float f) {
    uint32_t x = __float_as_uint(f);
    return (u16)((x + 0x7fffu + ((x >> 16) & 1u)) >> 16);
}
// async global->LDS, 16B per lane; lds dest = wave-uniform base + lane*16
__device__ __forceinline__ void load16(const void* g, void* l) {
    __builtin_amdgcn_global_load_lds(
        (const __attribute__((address_space(1))) uint32_t*)(uintptr_t)g,
        (__attribute__((address_space(3))) uint32_t*)(uint32_t)(uintptr_t)l,
        16, 0, 0);
}
// 8 consecutive f32 -> bf16x8
__device__ __forceinline__ bf16x8 ld8f(const float* f) {
    float4 a = *(const float4*)f;
    float4 b = *(const float4*)(f + 4);
    bf16x8 o;
    o[0] = (__bf16)a.x; o[1] = (__bf16)a.y; o[2] = (__bf16)a.z; o[3] = (__bf16)a.w;
    o[4] = (__bf16)b.x; o[5] = (__bf16)b.y; o[6] = (__bf16)b.z; o[7] = (__bf16)b.w;
    return o;
}

// ---------------------------------------------------------------------------
// Kernel 0: f32 -> bf16 conversion of q,k,v,Wq,Wk,Wv,Wo. grid (2048, 7).
// ---------------------------------------------------------------------------
__global__ __launch_bounds__(256) void convert_k(
    const float* __restrict__ q, const float* __restrict__ k, const float* __restrict__ v,
    const float* __restrict__ Wq, const float* __restrict__ Wk,
    const float* __restrict__ Wv, const float* __restrict__ Wo,
    u16* __restrict__ qb, u16* __restrict__ kb, u16* __restrict__ vb,
    u16* __restrict__ wqb, u16* __restrict__ wkb, u16* __restrict__ wvb,
    u16* __restrict__ wob)
{
    const float* src; u16* dst; int n8;
    switch (blockIdx.y) {
        case 0: src = q;  dst = qb;  n8 = 524288; break;
        case 1: src = k;  dst = kb;  n8 = 524288; break;
        case 2: src = v;  dst = vb;  n8 = 524288; break;
        case 3: src = Wq; dst = wqb; n8 = 131072; break;
        case 4: src = Wk; dst = wkb; n8 = 131072; break;
        case 5: src = Wv; dst = wvb; n8 = 131072; break;
        default: src = Wo; dst = wob; n8 = 131072; break;
    }
    int i = blockIdx.x * 256 + threadIdx.x;
    if (i >= n8) return;
    bf16x8 o = ld8f(src + (size_t)i * 8);
    *(bf16x8*)(dst + (size_t)i * 8) = o;
}

// ---------------------------------------------------------------------------
// Kernel 1: bf16 QKV projection + bias + RoPE + head split. Double-buffered.
// Grid (24, 32); 128x128 tile, BK=32, global_load_lds, 1 barrier/tile.
// ---------------------------------------------------------------------------
__global__ __launch_bounds__(256) void gemm_proj_b(
    const u16* __restrict__ qb, const u16* __restrict__ kb, const u16* __restrict__ vb,
    const u16* __restrict__ wqb, const u16* __restrict__ wkb, const u16* __restrict__ wvb,
    const float* __restrict__ bq, const float* __restrict__ bk, const float* __restrict__ bv,
    const float* __restrict__ sin_enc,
    u16* __restrict__ qh, u16* __restrict__ kh, u16* __restrict__ vt)
{
    __shared__ __align__(16) u16 lA[2][128 * 32];
    __shared__ __align__(16) u16 lB[2][128 * 32];
    const int t = threadIdx.x, wave = t >> 6, lane = t & 63;
    const int bx = blockIdx.x;
    const int w_idx = bx >> 3;
    const int n0 = (bx & 7) << 7;
    const int m0 = blockIdx.y << 7;
    const u16* A = (w_idx == 0) ? qb : (w_idx == 1 ? kb : vb);
    const u16* W = (w_idx == 0) ? wqb : (w_idx == 1 ? wkb : wvb);
    const float* bias = (w_idx == 0) ? bq : (w_idx == 1 ? bk : bv);

    const int wr = wave >> 1, wc = wave & 1;
    const int col16 = lane & 15, g16 = lane >> 4;
    f32x4 acc[4][4] = {};

    const int r0  = wave * 32 + (lane >> 2);
    const int kc8 = (lane & 3) << 3;
    const u16* gA = A + (size_t)(m0 + r0) * 1024 + kc8;
    const u16* gB = W + (size_t)(n0 + r0) * 1024 + kc8;

#define PROJ_STAGE(kk, buf)                                             \
    do {                                                                \
        char* a0 = (char*)lA[buf] + wave * 2048;                        \
        char* b0 = (char*)lB[buf] + wave * 2048;                        \
        load16(gA + (kk), a0);                                          \
        load16(gA + (kk) + 16 * 1024, a0 + 1024);                       \
        load16(gB + (kk), b0);                                          \
        load16(gB + (kk) + 16 * 1024, b0 + 1024);                       \
    } while (0)

#define PROJ_COMPUTE(buf)                                               \
    do {                                                                \
        const u16* pA = lA[buf] + (wr * 64 + col16) * 32 + g16 * 8;     \
        const u16* pB = lB[buf] + (wc * 64 + col16) * 32 + g16 * 8;     \
        bf16x8 af[4], bfr[4];                                           \
        _Pragma("unroll")                                               \
        for (int i = 0; i < 4; i++) {                                   \
            af[i]  = *(const bf16x8*)(pA + i * 512);                    \
            bfr[i] = *(const bf16x8*)(pB + i * 512);                    \
        }                                                               \
        _Pragma("unroll")                                               \
        for (int mi = 0; mi < 4; mi++)                                  \
            _Pragma("unroll")                                           \
            for (int ni = 0; ni < 4; ni++)                              \
                acc[mi][ni] = MFMA16(af[mi], bfr[ni], acc[mi][ni]);     \
    } while (0)

    PROJ_STAGE(0, 0);
    for (int kk = 0; kk < 1024; kk += 64) {
        __syncthreads();                    // drains buf0 loads (tile kk)
        if (kk + 32 < 1024) PROJ_STAGE(kk + 32, 1);   // in flight over compute
        PROJ_COMPUTE(0);
        __syncthreads();                    // drains buf1 loads (tile kk+32)
        if (kk + 64 < 1024) PROJ_STAGE(kk + 64, 0);
        PROJ_COMPUTE(1);
    }
#undef PROJ_STAGE
#undef PROJ_COMPUTE

#pragma unroll
    for (int ni = 0; ni < 4; ni++) {
        const int n = n0 + wc * 64 + ni * 16 + col16;
        const float bn = bias[n];
        const int h = n >> 6, hd = n & 63;
#pragma unroll
        for (int mi = 0; mi < 4; mi++) {
#pragma unroll
            for (int r = 0; r < 4; r++) {
                const int m = m0 + wr * 64 + mi * 16 + g16 * 4 + r;
                const int b = m >> 9, l = m & 511;
                float x = acc[mi][ni][r] + bn;
                if (w_idx == 2) {
                    vt[((size_t)(b * 16 + h) * 64 + hd) * 512 + l] = f2b(x);
                } else {
                    float partner = __shfl_xor(x, 1);
                    float s = sin_enc[(size_t)l * 1024 + (n & ~1)];
                    float c = sin_enc[(size_t)l * 1024 + (n | 1)];
                    float y = (n & 1) ? (x * c + partner * s) : (x * c - partner * s);
                    if (w_idx == 0) y *= 0.125f;
                    u16* dst = (w_idx == 0) ? qh : kh;
                    dst[((size_t)(b * 16 + h) * 512 + l) * 64 + hd] = f2b(y);
                }
            }
        }
    }
}

// ---------------------------------------------------------------------------
// Kernel 1 (fallback, ws < 64 MiB): f32 staging path (round-3, verified).
// ---------------------------------------------------------------------------
__global__ __launch_bounds__(256) void gemm_proj_f32(
    const float* __restrict__ qin, const float* __restrict__ kin, const float* __restrict__ vin,
    const float* __restrict__ Wq, const float* __restrict__ bq,
    const float* __restrict__ Wk, const float* __restrict__ bk,
    const float* __restrict__ Wv, const float* __restrict__ bv,
    const float* __restrict__ sin_enc,
    u16* __restrict__ qh, u16* __restrict__ kh, u16* __restrict__ vt)
{
    __shared__ __align__(16) u16 lA[128 * 32];
    __shared__ __align__(16) u16 lB[128 * 32];
    const int t = threadIdx.x, wave = t >> 6, lane = t & 63;
    const int bx = blockIdx.x;
    const int w_idx = bx >> 3;
    const int n0 = (bx & 7) << 7;
    const int m0 = blockIdx.y << 7;
    const float* A    = (w_idx == 0) ? qin : (w_idx == 1 ? kin : vin);
    const float* W    = (w_idx == 0) ? Wq  : (w_idx == 1 ? Wk  : Wv);
    const float* bias = (w_idx == 0) ? bq  : (w_idx == 1 ? bk  : bv);

    const int wr = wave >> 1, wc = wave & 1;
    const int col16 = lane & 15, g16 = lane >> 4;
    f32x4 acc[4][4] = {};

    const int c0   = wave * 128 + lane;
    const int row0 = c0 >> 2;
    const int kp   = (c0 & 3) << 3;
    const size_t gA0 = (size_t)(m0 + row0) * 1024 + kp;
    const size_t gB0 = (size_t)(n0 + row0) * 1024 + kp;
    u16* wA0 = lA + c0 * 8;
    u16* wA1 = lA + (c0 + 64) * 8;
    u16* wB0 = lB + c0 * 8;
    u16* wB1 = lB + (c0 + 64) * 8;

    bf16x8 ra0 = ld8f(A + gA0);
    bf16x8 ra1 = ld8f(A + gA0 + 16 * 1024);
    bf16x8 rb0 = ld8f(W + gB0);
    bf16x8 rb1 = ld8f(W + gB0 + 16 * 1024);

    for (int kk = 32; kk <= 1024; kk += 32) {
        __syncthreads();
        *(bf16x8*)wA0 = ra0; *(bf16x8*)wA1 = ra1;
        *(bf16x8*)wB0 = rb0; *(bf16x8*)wB1 = rb1;
        __syncthreads();
        if (kk < 1024) {
            ra0 = ld8f(A + gA0 + kk);
            ra1 = ld8f(A + gA0 + kk + 16 * 1024);
            rb0 = ld8f(W + gB0 + kk);
            rb1 = ld8f(W + gB0 + kk + 16 * 1024);
        }
        const u16* pA = lA + (wr * 64 + col16) * 32 + g16 * 8;
        const u16* pB = lB + (wc * 64 + col16) * 32 + g16 * 8;
        bf16x8 af[4], bfr[4];
#pragma unroll
        for (int i = 0; i < 4; i++) {
            af[i]  = *(const bf16x8*)(pA + i * 512);
            bfr[i] = *(const bf16x8*)(pB + i * 512);
        }
#pragma unroll
        for (int mi = 0; mi < 4; mi++)
#pragma unroll
            for (int ni = 0; ni < 4; ni++)
                acc[mi][ni] = MFMA16(af[mi], bfr[ni], acc[mi][ni]);
    }

#pragma unroll
    for (int ni = 0; ni < 4; ni++) {
        const int n = n0 + wc * 64 + ni * 16 + col16;
        const float bn = bias[n];
        const int h = n >> 6, hd = n & 63;
#pragma unroll
        for (int mi = 0; mi < 4; mi++) {
#pragma unroll
            for (int r = 0; r < 4; r++) {
                const int m = m0 + wr * 64 + mi * 16 + g16 * 4 + r;
                const int b = m >> 9, l = m & 511;
                float x = acc[mi][ni][r] + bn;
                if (w_idx == 2) {
                    vt[((size_t)(b * 16 + h) * 64 + hd) * 512 + l] = f2b(x);
                } else {
                    float partner = __shfl_xor(x, 1);
                    float s = sin_enc[(size_t)l * 1024 + (n & ~1)];
                    float c = sin_enc[(size_t)l * 1024 + (n | 1)];
                    float y = (n & 1) ? (x * c + partner * s) : (x * c - partner * s);
                    if (w_idx == 0) y *= 0.125f;
                    u16* dst = (w_idx == 0) ? qh : kh;
                    dst[((size_t)(b * 16 + h) * 512 + l) * 64 + hd] = f2b(y);
                }
            }
        }
    }
}

// ---------------------------------------------------------------------------
// Kernel 2: flash attention with dist bias + key mask.
// Grid 1024, 256 thr. dist staged via coalesced int4 -> u8 LDS tile.
// ---------------------------------------------------------------------------
__global__ __launch_bounds__(256) void attn_kernel(
    const u16* __restrict__ qh, const u16* __restrict__ kh, const u16* __restrict__ vt,
    const float* __restrict__ demb_g, const int* __restrict__ length,
    const int* __restrict__ dist, u16* __restrict__ ctx)
{
    __shared__ __align__(16) u16 Qs[64 * 64];
    __shared__ __align__(16) u16 Ks[64 * 64];
    __shared__ __align__(16) u16 Vs[64 * 64];
    __shared__ __align__(16) u16 Ps[4][16 * 64];
    __shared__ __align__(16) uint8_t Ds[64 * 64];   // dist codes for current tile
    __shared__ float demb[64];

    const int t = threadIdx.x, wave = t >> 6, lane = t & 63;
    const int bxx = blockIdx.x;
    const int qt = bxx & 7, bh = bxx >> 3;
    const int b = bh >> 4, h = bh & 15;
    if (t < 64) demb[t] = demb_g[t * 16 + h];
    const int len_b = length[b];
    const int ktmax = (len_b + 63) >> 6;   // masked tiles give exactly p=0; skip
    const int col16 = lane & 15, g16 = lane >> 4;
    const int c0 = wave * 128 + lane, c1 = c0 + 64;

    const u16* qbase = qh + (size_t)(bh * 512 + qt * 64) * 64;
    {
        uint4 rq0 = *(const uint4*)(qbase + c0 * 8);
        uint4 rq1 = *(const uint4*)(qbase + c1 * 8);
        *(uint4*)((char*)Qs + c0 * 16) = rq0;
        *(uint4*)((char*)Qs + c1 * 16) = rq1;
    }

    const u16* kbase = kh + (size_t)bh * 512 * 64;
    const u16* vbase = vt + (size_t)bh * 64 * 512;
    const int qrow_base = qt * 64 + wave * 16 + g16 * 4;

    // dist staging: thread t covers row t>>2 (of 64), cols (t&3)*16 .. +15
    const int drow = t >> 2;
    const int dcol = (t & 3) << 4;
    const int* dg = dist + (size_t)b * 512 * 512 + (size_t)(qt * 64 + drow) * 512 + dcol;
    uint32_t* DsW = (uint32_t*)(Ds + drow * 64 + dcol);

    // preload kt=0 K/V + dist
    uint4 rk0 = *(const uint4*)(kbase + c0 * 8);
    uint4 rk1 = *(const uint4*)(kbase + c1 * 8);
    uint4 rv0 = *(const uint4*)(vbase + (size_t)(c0 >> 3) * 512 + (c0 & 7) * 8);
    uint4 rv1 = *(const uint4*)(vbase + (size_t)(c1 >> 3) * 512 + (c1 & 7) * 8);
    int4 dd[4];
#pragma unroll
    for (int j = 0; j < 4; j++) dd[j] = *(const int4*)(dg + j * 4);

    __syncthreads();
    const u16* pQ = Qs + (wave * 16 + col16) * 64 + g16 * 8;
    const bf16x8 qa0 = *(const bf16x8*)pQ;
    const bf16x8 qa1 = *(const bf16x8*)(pQ + 32);

    f32x4 oacc[4] = {};
    float mrow[4], lrow[4];
#pragma unroll
    for (int r = 0; r < 4; r++) { mrow[r] = -1e30f; lrow[r] = 0.f; }

    for (int kt = 0; kt < ktmax; kt++) {
        __syncthreads();   // prior iteration's Ks/Vs/Ps/Ds reads done
        *(uint4*)((char*)Ks + c0 * 16) = rk0;
        *(uint4*)((char*)Ks + c1 * 16) = rk1;
        *(uint4*)((char*)Vs + c0 * 16) = rv0;
        *(uint4*)((char*)Vs + c1 * 16) = rv1;
#pragma unroll
        for (int j = 0; j < 4; j++)
            DsW[j] = (uint32_t)(dd[j].x & 63) | ((uint32_t)(dd[j].y & 63) << 8) |
                     ((uint32_t)(dd[j].z & 63) << 16) | ((uint32_t)(dd[j].w & 63) << 24);
        __syncthreads();
        if (kt + 1 < ktmax) {   // prefetch next tile (overlaps compute)
            const u16* kb = kbase + (size_t)(kt + 1) * 64 * 64;
            rk0 = *(const uint4*)(kb + c0 * 8);
            rk1 = *(const uint4*)(kb + c1 * 8);
            rv0 = *(const uint4*)(vbase + (size_t)(c0 >> 3) * 512 + (kt + 1) * 64 + (c0 & 7) * 8);
            rv1 = *(const uint4*)(vbase + (size_t)(c1 >> 3) * 512 + (kt + 1) * 64 + (c1 & 7) * 8);
            const int* dgn = dg + (kt + 1) * 64;
#pragma unroll
            for (int j = 0; j < 4; j++) dd[j] = *(const int4*)(dgn + j * 4);
        }

        f32x4 sacc[4] = {};
#pragma unroll
        for (int ni = 0; ni < 4; ni++) {
            const u16* pK = Ks + (ni * 16 + col16) * 64 + g16 * 8;
            bf16x8 kf0 = *(const bf16x8*)pK;
            bf16x8 kf1 = *(const bf16x8*)(pK + 32);
            sacc[ni] = MFMA16(qa0, kf0, sacc[ni]);
            sacc[ni] = MFMA16(qa1, kf1, sacc[ni]);
        }

        float rmax[4] = {-1e30f, -1e30f, -1e30f, -1e30f};
        const int qrl = wave * 16 + g16 * 4;   // local q row of r=0
#pragma unroll
        for (int ni = 0; ni < 4; ni++) {
            const int kcl = ni * 16 + col16;
            const bool masked = (kt * 64 + kcl) >= len_b;
#pragma unroll
            for (int r = 0; r < 4; r++) {
                float s = sacc[ni][r] + demb[Ds[(qrl + r) * 64 + kcl]];
                s = masked ? -1e9f : s;
                sacc[ni][r] = s;
                rmax[r] = fmaxf(rmax[r], s);
            }
        }
#pragma unroll
        for (int off = 1; off < 16; off <<= 1)
#pragma unroll
            for (int r = 0; r < 4; r++) rmax[r] = fmaxf(rmax[r], __shfl_xor(rmax[r], off));

        float alpha[4], rsum[4];
#pragma unroll
        for (int r = 0; r < 4; r++) {
            float mn = fmaxf(mrow[r], rmax[r]);
            alpha[r] = __expf(mrow[r] - mn);
            mrow[r] = mn;
            rsum[r] = 0.f;
        }
#pragma unroll
        for (int ni = 0; ni < 4; ni++)
#pragma unroll
            for (int r = 0; r < 4; r++) {
                float p = __expf(sacc[ni][r] - mrow[r]);
                sacc[ni][r] = p;
                rsum[r] += p;
            }
#pragma unroll
        for (int off = 1; off < 16; off <<= 1)
#pragma unroll
            for (int r = 0; r < 4; r++) rsum[r] += __shfl_xor(rsum[r], off);
#pragma unroll
        for (int r = 0; r < 4; r++) lrow[r] = lrow[r] * alpha[r] + rsum[r];
#pragma unroll
        for (int di = 0; di < 4; di++)
#pragma unroll
            for (int r = 0; r < 4; r++) oacc[di][r] *= alpha[r];

        u16* Pw = &Ps[wave][0];
#pragma unroll
        for (int ni = 0; ni < 4; ni++)
#pragma unroll
            for (int r = 0; r < 4; r++)
                Pw[(g16 * 4 + r) * 64 + ni * 16 + col16] = f2b(sacc[ni][r]);
        __syncthreads();

        const u16* pP = Pw + col16 * 64 + g16 * 8;
        bf16x8 pa0 = *(const bf16x8*)pP;
        bf16x8 pa1 = *(const bf16x8*)(pP + 32);
#pragma unroll
        for (int di = 0; di < 4; di++) {
            const u16* pV = Vs + (di * 16 + col16) * 64 + g16 * 8;
            bf16x8 vf0 = *(const bf16x8*)pV;
            bf16x8 vf1 = *(const bf16x8*)(pV + 32);
            oacc[di] = MFMA16(pa0, vf0, oacc[di]);
            oacc[di] = MFMA16(pa1, vf1, oacc[di]);
        }
    }

#pragma unroll
    for (int di = 0; di < 4; di++)
#pragma unroll
        for (int r = 0; r < 4; r++) {
            const int qrow = qrow_base + r;
            const int d = di * 16 + col16;
            const float inv_l = 1.0f / fmaxf(lrow[r], 1e-30f);
            ctx[(size_t)(b * 512 + qrow) * 1024 + h * 64 + d] = f2b(oacc[di][r] * inv_l);
        }
}

// ---------------------------------------------------------------------------
// Kernel 3: ctx(bf16) @ Wo^T(bf16) + bo -> f32. 64x128 tiles, dbuf. Grid (8,64).
// ---------------------------------------------------------------------------
__global__ __launch_bounds__(256) void gemm_out_b(
    const u16* __restrict__ ctx, const u16* __restrict__ wob,
    const float* __restrict__ bo, float* __restrict__ out)
{
    __shared__ __align__(16) u16 lA[2][64 * 32];
    __shared__ __align__(16) u16 lB[2][128 * 32];
    const int t = threadIdx.x, wave = t >> 6, lane = t & 63;
    const int n0 = blockIdx.x << 7;
    const int m0 = blockIdx.y << 6;
    const int col16 = lane & 15, g16 = lane >> 4;
    f32x4 acc[4][2] = {};

    // A: 64x32 tile = 256 chunks, 1/thread; B: 128x32 = 512 chunks, 2/thread
    const int cA = wave * 64 + lane;
    const u16* gA = ctx + (size_t)(m0 + (cA >> 2)) * 1024 + ((cA & 3) << 3);
    const int cB = wave * 128 + lane;
    const u16* gB = wob + (size_t)(n0 + (cB >> 2)) * 1024 + ((cB & 3) << 3);

#define OUT_STAGE(kk, buf)                                              \
    do {                                                                \
        char* a0 = (char*)lA[buf] + wave * 1024;                        \
        char* b0 = (char*)lB[buf] + wave * 2048;                        \
        load16(gA + (kk), a0);                                          \
        load16(gB + (kk), b0);                                          \
        load16(gB + (kk) + 16 * 1024, b0 + 1024);                       \
    } while (0)

#define OUT_COMPUTE(buf)                                                \
    do {                                                                \
        const u16* pA = lA[buf] + col16 * 32 + g16 * 8;                 \
        const u16* pB = lB[buf] + (wave * 32 + col16) * 32 + g16 * 8;   \
        bf16x8 af[4], bfr[2];                                           \
        _Pragma("unroll")                                               \
        for (int i = 0; i < 4; i++) af[i] = *(const bf16x8*)(pA + i * 512); \
        _Pragma("unroll")                                               \
        for (int i = 0; i < 2; i++) bfr[i] = *(const bf16x8*)(pB + i * 512); \
        _Pragma("unroll")                                               \
        for (int mi = 0; mi < 4; mi++)                                  \
            _Pragma("unroll")                                           \
            for (int ni = 0; ni < 2; ni++)                              \
                acc[mi][ni] = MFMA16(af[mi], bfr[ni], acc[mi][ni]);     \
    } while (0)

    OUT_STAGE(0, 0);
    for (int kk = 0; kk < 1024; kk += 64) {
        __syncthreads();
        if (kk + 32 < 1024) OUT_STAGE(kk + 32, 1);
        OUT_COMPUTE(0);
        __syncthreads();
        if (kk + 64 < 1024) OUT_STAGE(kk + 64, 0);
        OUT_COMPUTE(1);
    }
#undef OUT_STAGE
#undef OUT_COMPUTE

#pragma unroll
    for (int ni = 0; ni < 2; ni++) {
        const int n = n0 + wave * 32 + ni * 16 + col16;
        const float bn = bo[n];
#pragma unroll
        for (int mi = 0; mi < 4; mi++)
#pragma unroll
            for (int r = 0; r < 4; r++) {
                const int m = m0 + mi * 16 + g16 * 4 + r;
                out[(size_t)m * 1024 + n] = acc[mi][ni][r] + bn;
            }
    }
}

// ---------------------------------------------------------------------------
// Kernel 3 (fallback): ctx(bf16) @ Wo^T(f32) + bo -> f32 (round-3 path).
// ---------------------------------------------------------------------------
__global__ __launch_bounds__(256) void gemm_out_f32(
    const u16* __restrict__ ctx, const float* __restrict__ Wo,
    const float* __restrict__ bo, float* __restrict__ out)
{
    __shared__ __align__(16) u16 lA[128 * 32];
    __shared__ __align__(16) u16 lB[128 * 32];
    const int t = threadIdx.x, wave = t >> 6, lane = t & 63;
    const int n0 = blockIdx.x << 7;
    const int m0 = blockIdx.y << 7;
    const int wr = wave >> 1, wc = wave & 1;
    const int col16 = lane & 15, g16 = lane >> 4;
    f32x4 acc[4][4] = {};

    const int c0   = wave * 128 + lane;
    const int row0 = c0 >> 2;
    const int kp   = (c0 & 3) << 3;
    const u16* gA = ctx + (size_t)(m0 + row0) * 1024 + kp;
    const size_t gB0 = (size_t)(n0 + row0) * 1024 + kp;
    u16* wA0 = lA + c0 * 8;
    u16* wA1 = lA + (c0 + 64) * 8;
    u16* wB0 = lB + c0 * 8;
    u16* wB1 = lB + (c0 + 64) * 8;

    uint4 ua0 = *(const uint4*)gA;
    uint4 ua1 = *(const uint4*)(gA + 16 * 1024);
    bf16x8 ra0 = *(bf16x8*)&ua0, ra1 = *(bf16x8*)&ua1;
    bf16x8 rb0 = ld8f(Wo + gB0);
    bf16x8 rb1 = ld8f(Wo + gB0 + 16 * 1024);

    for (int kk = 32; kk <= 1024; kk += 32) {
        __syncthreads();
        *(bf16x8*)wA0 = ra0; *(bf16x8*)wA1 = ra1;
        *(bf16x8*)wB0 = rb0; *(bf16x8*)wB1 = rb1;
        __syncthreads();
        if (kk < 1024) {
            uint4 t0 = *(const uint4*)(gA + kk);
            uint4 t1 = *(const uint4*)(gA + kk + 16 * 1024);
            ra0 = *(bf16x8*)&t0; ra1 = *(bf16x8*)&t1;
            rb0 = ld8f(Wo + gB0 + kk);
            rb1 = ld8f(Wo + gB0 + kk + 16 * 1024);
        }
        const u16* pA = lA + (wr * 64 + col16) * 32 + g16 * 8;
        const u16* pB = lB + (wc * 64 + col16) * 32 + g16 * 8;
        bf16x8 af[4], bfr[4];
#pragma unroll
        for (int i = 0; i < 4; i++) {
            af[i]  = *(const bf16x8*)(pA + i * 512);
            bfr[i] = *(const bf16x8*)(pB + i * 512);
        }
#pragma unroll
        for (int mi = 0; mi < 4; mi++)
#pragma unroll
            for (int ni = 0; ni < 4; ni++)
                acc[mi][ni] = MFMA16(af[mi], bfr[ni], acc[mi][ni]);
    }

#pragma unroll
    for (int ni = 0; ni < 4; ni++) {
        const int n = n0 + wc * 64 + ni * 16 + col16;
        const float bn = bo[n];
#pragma unroll
        for (int mi = 0; mi < 4; mi++)
#pragma unroll
            for (int r = 0; r < 4; r++) {
                const int m = m0 + wr * 64 + mi * 16 + g16 * 4 + r;
                out[(size_t)m * 1024 + n] = acc[mi][ni][r] + bn;
            }
    }
}

extern "C" void kernel_launch(void* const* d_in, const int* in_sizes, int n_in,
                              void* d_out, int out_size, void* d_ws, size_t ws_size,
                              hipStream_t stream) {
    const float* q       = (const float*)d_in[0];
    const float* k       = (const float*)d_in[1];
    const float* v       = (const float*)d_in[2];
    const float* Wq      = (const float*)d_in[3];
    const float* bq      = (const float*)d_in[4];
    const float* Wk      = (const float*)d_in[5];
    const float* bk      = (const float*)d_in[6];
    const float* Wv      = (const float*)d_in[7];
    const float* bv      = (const float*)d_in[8];
    const float* Wo      = (const float*)d_in[9];
    const float* bo      = (const float*)d_in[10];
    const float* demb    = (const float*)d_in[11];
    const float* sin_enc = (const float*)d_in[12];
    const int* length    = (const int*)d_in[13];
    const int* dist      = (const int*)d_in[14];

    const size_t SLOT = 4194304;          // 8 MiB region, in u16 elements
    u16* qh  = (u16*)d_ws;
    u16* kh  = qh + SLOT;
    u16* vt  = kh + SLOT;
    u16* ctx = vt + SLOT;

    if (ws_size >= (size_t)64 * 1024 * 1024) {
        u16* qb  = ctx + SLOT;
        u16* kb  = qb + SLOT;
        u16* vb  = kb + SLOT;
        u16* wqb = vb + SLOT;
        u16* wkb = wqb + 1048576;
        u16* wvb = wkb + 1048576;
        u16* wob = wvb + 1048576;
        convert_k<<<dim3(2048, 7), 256, 0, stream>>>(q, k, v, Wq, Wk, Wv, Wo,
                                                     qb, kb, vb, wqb, wkb, wvb, wob);
        gemm_proj_b<<<dim3(24, 32), 256, 0, stream>>>(qb, kb, vb, wqb, wkb, wvb,
                                                      bq, bk, bv, sin_enc, qh, kh, vt);
        attn_kernel<<<dim3(1024), 256, 0, stream>>>(qh, kh, vt, demb, length, dist, ctx);
        gemm_out_b<<<dim3(8, 64), 256, 0, stream>>>(ctx, wob, bo, (float*)d_out);
    } else {
        gemm_proj_f32<<<dim3(24, 32), 256, 0, stream>>>(q, k, v, Wq, bq, Wk, bk, Wv, bv,
                                                        sin_enc, qh, kh, vt);
        attn_kernel<<<dim3(1024), 256, 0, stream>>>(qh, kh, vt, demb, length, dist, ctx);
        gemm_out_f32<<<dim3(8, 32), 256, 0, stream>>>(ctx, Wo, bo, (float*)d_out);
    }
}